// Round 15
// baseline (231.929 us; speedup 1.0000x reference)
//
#include <hip/hip_runtime.h>
#include <cstdio>

#define NN 100000
#define NE 1600000
#define IN_DIM 256
#define HID_DIM 128
#define OUT_DIM 64

#define EPB 4096                         // edges per scat block
#define NBLK ((NE + EPB - 1) / EPB)      // 391
#define FBSH 7
#define FBN 128                          // nodes per fine bucket
#define NFB 782                          // ceil(NN/128)
#define CAP 2560                         // per-bucket capacity (mean 2048, +11 sigma)
#define PREP_ELEMS (HID_DIM * IN_DIM + OUT_DIM * HID_DIM)  // 40960
#define PREP_BLKS ((PREP_ELEMS + 127) / 128)               // 320

typedef short s8v __attribute__((ext_vector_type(8)));
typedef float f4v __attribute__((ext_vector_type(4)));
typedef _Float16 h2v __attribute__((ext_vector_type(2)));
typedef unsigned u32x4 __attribute__((ext_vector_type(4)));
typedef unsigned short u16x4 __attribute__((ext_vector_type(4)));
typedef unsigned short u16x8 __attribute__((ext_vector_type(8)));
typedef int i32x4 __attribute__((ext_vector_type(4)));

__device__ __forceinline__ unsigned short f2bf(float f) {
    unsigned u = __builtin_bit_cast(unsigned, f);
    u += 0x7FFFu + ((u >> 16) & 1u);  // RNE
    return (unsigned short)(u >> 16);
}
__device__ __forceinline__ unsigned short f2h(float f) {
    return __builtin_bit_cast(unsigned short, (_Float16)f);
}
__device__ __forceinline__ h2v bch2(unsigned w) { return __builtin_bit_cast(h2v, w); }

// ---------------- scat1: per-(block,bucket) counts for dst and src (int4 loads) ----------
__global__ __launch_bounds__(256) void scat1_kernel(const int* __restrict__ src,
                                                    const int* __restrict__ dst,
                                                    unsigned short* __restrict__ cnt2dD,
                                                    unsigned short* __restrict__ cnt2dS) {
    __shared__ unsigned hbD[NFB], hbS[NFB];
    const int t = threadIdx.x;
    for (int i = t; i < NFB; i += 256) { hbD[i] = 0u; hbS[i] = 0u; }
    __syncthreads();
    const int base = blockIdx.x * EPB;
    int n = NE - base; if (n > EPB) n = EPB;
    const i32x4* d4 = reinterpret_cast<const i32x4*>(dst + base);
    const i32x4* s4 = reinterpret_cast<const i32x4*>(src + base);
    const int nq = n >> 2;
    for (int i = t; i < nq; i += 256) {
        i32x4 d = d4[i];
        i32x4 s = s4[i];
#pragma unroll
        for (int k = 0; k < 4; ++k) {
            atomicAdd(&hbD[(unsigned)d[k] >> FBSH], 1u);
            atomicAdd(&hbS[(unsigned)s[k] >> FBSH], 1u);
        }
    }
    for (int i = (nq << 2) + t; i < n; i += 256) {
        atomicAdd(&hbD[dst[base + i] >> FBSH], 1u);
        atomicAdd(&hbS[src[base + i] >> FBSH], 1u);
    }
    __syncthreads();
    const size_t row = (size_t)blockIdx.x * NFB;
    for (int i = t; i < NFB; i += 256) {
        cnt2dD[row + i] = (unsigned short)hbD[i];
        cnt2dS[row + i] = (unsigned short)hbS[i];
    }
}

// ---- scanC + weight prep fused ----
__global__ __launch_bounds__(128) void scanCprep_kernel(unsigned short* __restrict__ cnt2dD,
                                                        unsigned short* __restrict__ cnt2dS,
                                                        unsigned* __restrict__ btotD,
                                                        unsigned* __restrict__ btotS,
                                                        const float* __restrict__ W1,
                                                        const float* __restrict__ W2,
                                                        unsigned short* __restrict__ W1t,
                                                        unsigned short* __restrict__ W2t) {
    const int g = blockIdx.x;
    if (g >= 2 * NFB) {  // weight prep path (bf16 transpose)
        int i = (g - 2 * NFB) * 128 + threadIdx.x;
        if (i < HID_DIM * IN_DIM) {
            int n = i >> 8, k = i & 255;
            W1t[i] = f2bf(W1[k * HID_DIM + n]);
        } else if (i < PREP_ELEMS) {
            int m = i - HID_DIM * IN_DIM;
            int n = m >> 7, k = m & 127;
            W2t[m] = f2bf(W2[k * OUT_DIM + n]);
        }
        return;
    }
    __shared__ unsigned sc[128];
    unsigned short* arr = (g < NFB) ? cnt2dD : cnt2dS;
    unsigned* btot = (g < NFB) ? btotD : btotS;
    const int b = (g < NFB) ? g : g - NFB;
    const int t = threadIdx.x;
    unsigned v[4];
    unsigned s = 0;
#pragma unroll
    for (int i = 0; i < 4; ++i) {
        int blk = t * 4 + i;
        unsigned x = (blk < NBLK) ? (unsigned)arr[(size_t)blk * NFB + b] : 0u;
        v[i] = s;
        s += x;
    }
    sc[t] = s;
    __syncthreads();
    for (int o = 1; o < 128; o <<= 1) {
        unsigned add = (t >= o) ? sc[t - o] : 0u;
        __syncthreads();
        sc[t] += add;
        __syncthreads();
    }
    unsigned incl = sc[t];
    unsigned excl = incl - s;
#pragma unroll
    for (int i = 0; i < 4; ++i) {
        int blk = t * 4 + i;
        if (blk < NBLK) arr[(size_t)blk * NFB + b] = (unsigned short)(excl + v[i]);
    }
    if (t == 127) btot[b] = incl;
}

// ---------------- scat2: scatter into CAP-strided bucket regions (int4 loads) ------------
__global__ __launch_bounds__(256) void scat2_kernel(const int* __restrict__ src,
                                                    const int* __restrict__ dst,
                                                    const unsigned short* __restrict__ ofsD,
                                                    const unsigned short* __restrict__ ofsS,
                                                    unsigned* __restrict__ ebufD,
                                                    unsigned char* __restrict__ ebufS) {
    __shared__ unsigned curD[NFB], curS[NFB];
    const int t = threadIdx.x;
    const size_t row = (size_t)blockIdx.x * NFB;
    for (int i = t; i < NFB; i += 256) {
        curD[i] = (unsigned)i * CAP + (unsigned)ofsD[row + i];
        curS[i] = (unsigned)i * CAP + (unsigned)ofsS[row + i];
    }
    __syncthreads();
    const int base = blockIdx.x * EPB;
    int n = NE - base; if (n > EPB) n = EPB;
    const i32x4* d4 = reinterpret_cast<const i32x4*>(dst + base);
    const i32x4* s4 = reinterpret_cast<const i32x4*>(src + base);
    const int nq = n >> 2;
    for (int i = t; i < nq; i += 256) {
        i32x4 d = d4[i];
        i32x4 s = s4[i];
#pragma unroll
        for (int k = 0; k < 4; ++k) {
            unsigned pD = atomicAdd(&curD[(unsigned)d[k] >> FBSH], 1u);
            ebufD[pD] = ((unsigned)(d[k] & 127) << 17) | (unsigned)s[k];
            unsigned pS = atomicAdd(&curS[(unsigned)s[k] >> FBSH], 1u);
            ebufS[pS] = (unsigned char)(s[k] & 127);
        }
    }
    for (int i = (nq << 2) + t; i < n; i += 256) {
        int d = dst[base + i];
        int s = src[base + i];
        unsigned pD = atomicAdd(&curD[d >> FBSH], 1u);
        ebufD[pD] = ((unsigned)(d & 127) << 17) | (unsigned)s;
        unsigned pS = atomicAdd(&curS[s >> FBSH], 1u);
        ebufS[pS] = (unsigned char)(s & 127);
    }
}

// ---- bsort + countB fused (u32x4 edge loads, 4-tag u32 loads) ----
__global__ __launch_bounds__(256) void bsortc_kernel(const unsigned* __restrict__ ebufD,
                                                     const unsigned* __restrict__ btotD,
                                                     const unsigned char* __restrict__ ebufS,
                                                     const unsigned* __restrict__ btotS,
                                                     int* __restrict__ csr,
                                                     unsigned* __restrict__ rsinfo,
                                                     float* __restrict__ dsin,
                                                     unsigned* __restrict__ cnt_out) {
    __shared__ unsigned hn[FBN];
    __shared__ unsigned sc[FBN];
    __shared__ unsigned cur[FBN];
    const int b = blockIdx.x;
    const int t = threadIdx.x;
    const unsigned e0 = (unsigned)b * CAP;
    const unsigned nD = btotD[b];
    if (t < FBN) hn[t] = 0u;
    __syncthreads();
    const u32x4* eD4 = reinterpret_cast<const u32x4*>(ebufD + e0);
    const int nDq = (int)(nD >> 2);
    for (int i = t; i < nDq; i += 256) {
        u32x4 v = eD4[i];
#pragma unroll
        for (int k = 0; k < 4; ++k) atomicAdd(&hn[(v[k] >> 17) & 127u], 1u);
    }
    for (unsigned j = (unsigned)(nDq << 2) + t; j < nD; j += 256)
        atomicAdd(&hn[(ebufD[e0 + j] >> 17) & 127u], 1u);
    __syncthreads();
    unsigned cnt_t = (t < FBN) ? hn[t] : 0u;
    if (t < FBN) sc[t] = cnt_t;
    __syncthreads();
    for (int o = 1; o < FBN; o <<= 1) {
        unsigned add = (t < FBN && t >= o) ? sc[t - o] : 0u;
        __syncthreads();
        if (t < FBN) sc[t] += add;
        __syncthreads();
    }
    if (t < FBN) {
        unsigned excl = sc[t] - cnt_t;
        cur[t] = e0 + excl;
        int node = (b << FBSH) + t;
        if (node < NN) {
            rsinfo[node] = ((e0 + excl) << 10) | (cnt_t & 1023u);
            dsin[node] = rsqrtf((float)(cnt_t ? cnt_t : 1u));
        }
    }
    __syncthreads();
    for (int i = t; i < nDq; i += 256) {
        u32x4 v = eD4[i];
#pragma unroll
        for (int k = 0; k < 4; ++k) {
            unsigned pos = atomicAdd(&cur[(v[k] >> 17) & 127u], 1u);
            csr[pos] = (int)(v[k] & 0x1FFFFu);
        }
    }
    for (unsigned j = (unsigned)(nDq << 2) + t; j < nD; j += 256) {
        unsigned pk = ebufD[e0 + j];
        unsigned pos = atomicAdd(&cur[(pk >> 17) & 127u], 1u);
        csr[pos] = (int)(pk & 0x1FFFFu);
    }
    // ---- phase 2: src-tag histogram -> cnt_out ----
    __syncthreads();
    if (t < FBN) hn[t] = 0u;
    __syncthreads();
    const unsigned nS = btotS[b];
    const unsigned* eS4 = reinterpret_cast<const unsigned*>(ebufS + e0);
    const int nSq = (int)(nS >> 2);
    for (int i = t; i < nSq; i += 256) {
        unsigned w = eS4[i];
        atomicAdd(&hn[w & 127u], 1u);
        atomicAdd(&hn[(w >> 8) & 127u], 1u);
        atomicAdd(&hn[(w >> 16) & 127u], 1u);
        atomicAdd(&hn[(w >> 24) & 127u], 1u);
    }
    for (unsigned j = (unsigned)(nSq << 2) + t; j < nS; j += 256)
        atomicAdd(&hn[ebufS[e0 + j]], 1u);
    __syncthreads();
    if (t < FBN) {
        int node = (b << FBSH) + t;
        if (node < NN) cnt_out[node] = hn[t];
    }
}

// ---- GEMM1 (MFMA bf16, pipelined): feat1 (slice-major f16 [8][NN][16]) ----
__global__ __launch_bounds__(256) void gemm1_kernel(const float* __restrict__ h,
                                                    const unsigned short* __restrict__ W1t,
                                                    const unsigned* __restrict__ cnt_out,
                                                    unsigned short* __restrict__ feat1, int M) {
    __shared__ unsigned short sA[2][128][40];  // 80B row stride, 16B aligned
    const int tid = threadIdx.x;
    const int lane = tid & 63;
    const int wave = tid >> 6;
    const int wm = wave >> 1, wn = wave & 1;
    const int m0 = blockIdx.x * 128;
    const int arow = tid >> 3;   // 0..31
    const int akq = tid & 7;     // float4 within 32 k

    f4v acc[4][4];
#pragma unroll
    for (int i = 0; i < 4; ++i)
#pragma unroll
        for (int j = 0; j < 4; ++j) acc[i][j] = (f4v)0.f;

    int mrow[4]; bool mok[4];
#pragma unroll
    for (int i = 0; i < 4; ++i) { mrow[i] = m0 + arow + i * 32; mok[i] = mrow[i] < M; }

    float4 pre[4];
#pragma unroll
    for (int i = 0; i < 4; ++i)
        pre[i] = mok[i] ? *reinterpret_cast<const float4*>(&h[(size_t)mrow[i] * IN_DIM + akq * 4])
                        : make_float4(0.f, 0.f, 0.f, 0.f);
#pragma unroll
    for (int i = 0; i < 4; ++i) {
        u16x4 p;
        p[0] = f2bf(pre[i].x); p[1] = f2bf(pre[i].y);
        p[2] = f2bf(pre[i].z); p[3] = f2bf(pre[i].w);
        *reinterpret_cast<u16x4*>(&sA[0][arow + i * 32][akq * 4]) = p;
    }
    __syncthreads();

    int cur = 0;
#pragma unroll
    for (int ks = 0; ks < 8; ++ks) {
        if (ks < 7) {
            const int k0n = (ks + 1) * 32;
#pragma unroll
            for (int i = 0; i < 4; ++i)
                pre[i] = mok[i] ? *reinterpret_cast<const float4*>(
                                      &h[(size_t)mrow[i] * IN_DIM + k0n + akq * 4])
                                : make_float4(0.f, 0.f, 0.f, 0.f);
        }
        s8v bfrag[4];
#pragma unroll
        for (int ni = 0; ni < 4; ++ni)
            bfrag[ni] = *reinterpret_cast<const s8v*>(
                &W1t[(size_t)(wn * 64 + ni * 16 + (lane & 15)) * IN_DIM + ks * 32 + (lane >> 4) * 8]);
        s8v afrag[4];
#pragma unroll
        for (int mi = 0; mi < 4; ++mi)
            afrag[mi] = *reinterpret_cast<const s8v*>(
                &sA[cur][wm * 64 + mi * 16 + (lane & 15)][(lane >> 4) * 8]);
#pragma unroll
        for (int ni = 0; ni < 4; ++ni)
#pragma unroll
            for (int mi = 0; mi < 4; ++mi)
                acc[mi][ni] = __builtin_amdgcn_mfma_f32_16x16x32_bf16(afrag[mi], bfrag[ni], acc[mi][ni], 0, 0, 0);
        if (ks < 7) {
#pragma unroll
            for (int i = 0; i < 4; ++i) {
                u16x4 p;
                p[0] = f2bf(pre[i].x); p[1] = f2bf(pre[i].y);
                p[2] = f2bf(pre[i].z); p[3] = f2bf(pre[i].w);
                *reinterpret_cast<u16x4*>(&sA[cur ^ 1][arow + i * 32][akq * 4]) = p;
            }
        }
        __syncthreads();
        cur ^= 1;
    }
    // epilogue: per-row dsout scale + f16 store, slice-major [slice][row][16]
#pragma unroll
    for (int mi = 0; mi < 4; ++mi) {
#pragma unroll
        for (int j = 0; j < 4; ++j) {
            int row = m0 + wm * 64 + mi * 16 + (lane >> 4) * 4 + j;
            if (row < M) {
                unsigned cdeg = cnt_out[row];
                float s = rsqrtf((float)(cdeg ? cdeg : 1u));
#pragma unroll
                for (int ni = 0; ni < 4; ++ni) {
                    int slice = wn * 4 + ni;
                    feat1[((size_t)slice * NN + row) * 16 + (lane & 15)] =
                        f2h(acc[mi][ni][j] * s);
                }
            }
        }
    }
}

// ---- GEMM2 (MFMA bf16, pipelined): feat2[M,64] (f16) = xs @ W2; xs slice-major bf16 ----
__global__ __launch_bounds__(256) void gemm2_kernel(const unsigned short* __restrict__ xs,
                                                    const unsigned short* __restrict__ W2t,
                                                    unsigned short* __restrict__ feat2, int M) {
    __shared__ unsigned short sA[2][128][40];
    const int tid = threadIdx.x;
    const int lane = tid & 63;
    const int wave = tid >> 6;
    const int wm = wave >> 1, wn = wave & 1;
    const int m0 = blockIdx.x * 128;

    f4v acc[4][2];
#pragma unroll
    for (int i = 0; i < 4; ++i)
#pragma unroll
        for (int j = 0; j < 2; ++j) acc[i][j] = (f4v)0.f;

    int srow[2], skq[2]; bool sok[2];
#pragma unroll
    for (int i = 0; i < 2; ++i) {
        int idx = tid + i * 256;
        srow[i] = idx >> 2; skq[i] = idx & 3;
        sok[i] = (m0 + srow[i]) < M;
    }

    u16x8 pre[2];
#pragma unroll
    for (int i = 0; i < 2; ++i)
        pre[i] = sok[i] ? *reinterpret_cast<const u16x8*>(
                              &xs[((size_t)(skq[i] >> 1) * NN + (m0 + srow[i])) * 16 +
                                  (skq[i] & 1) * 8])
                        : (u16x8)0;
#pragma unroll
    for (int i = 0; i < 2; ++i)
        *reinterpret_cast<u16x8*>(&sA[0][srow[i]][skq[i] * 8]) = pre[i];
    __syncthreads();

    int cur = 0;
#pragma unroll
    for (int ks = 0; ks < 4; ++ks) {
        if (ks < 3) {
#pragma unroll
            for (int i = 0; i < 2; ++i)
                pre[i] = sok[i] ? *reinterpret_cast<const u16x8*>(
                                      &xs[((size_t)(2 * (ks + 1) + (skq[i] >> 1)) * NN +
                                           (m0 + srow[i])) * 16 + (skq[i] & 1) * 8])
                                : (u16x8)0;
        }
        s8v bfrag[2];
#pragma unroll
        for (int ni = 0; ni < 2; ++ni)
            bfrag[ni] = *reinterpret_cast<const s8v*>(
                &W2t[(size_t)(wn * 32 + ni * 16 + (lane & 15)) * HID_DIM + ks * 32 + (lane >> 4) * 8]);
        s8v afrag[4];
#pragma unroll
        for (int mi = 0; mi < 4; ++mi)
            afrag[mi] = *reinterpret_cast<const s8v*>(
                &sA[cur][wm * 64 + mi * 16 + (lane & 15)][(lane >> 4) * 8]);
#pragma unroll
        for (int ni = 0; ni < 2; ++ni)
#pragma unroll
            for (int mi = 0; mi < 4; ++mi)
                acc[mi][ni] = __builtin_amdgcn_mfma_f32_16x16x32_bf16(afrag[mi], bfrag[ni], acc[mi][ni], 0, 0, 0);
        if (ks < 3) {
#pragma unroll
            for (int i = 0; i < 2; ++i)
                *reinterpret_cast<u16x8*>(&sA[cur ^ 1][srow[i]][skq[i] * 8]) = pre[i];
        }
        __syncthreads();
        cur ^= 1;
    }
#pragma unroll
    for (int mi = 0; mi < 4; ++mi)
#pragma unroll
        for (int ni = 0; ni < 2; ++ni) {
            int col = wn * 32 + ni * 16 + (lane & 15);
#pragma unroll
            for (int j = 0; j < 4; ++j) {
                int row = m0 + wm * 64 + mi * 16 + (lane >> 4) * 4 + j;
                if (row < M) feat2[(size_t)row * OUT_DIM + col] = f2h(acc[mi][ni][j]);
            }
        }
}

// ---- SpMM layer 1 v3: 8-way slice-pinned (slice = blockIdx&7 -> XCD round-robin),
//      4 nodes/wave, 8 edge-slots x 2 hw lanes, shfl-amortized csr staging ----
__global__ __launch_bounds__(256) void spmm1_kernel(const unsigned short* __restrict__ feat,
                                                    const int* __restrict__ csr,
                                                    const unsigned* __restrict__ rsinfo,
                                                    const float* __restrict__ dsin,
                                                    const unsigned* __restrict__ cnt_out,
                                                    const float* __restrict__ b1,
                                                    unsigned short* __restrict__ xs) {
    const int lane = threadIdx.x & 63;
    const int wave = threadIdx.x >> 6;
    const int s = blockIdx.x & 7;                  // feature slice -> XCD via round-robin
    const int node = (blockIdx.x >> 3) * 16 + wave * 4 + (lane >> 4);  // NN = 16*6250 exact
    const int n4 = (lane >> 4) << 4;               // shfl base for my node's 16-lane group
    const int slot = (lane >> 1) & 7;              // edge slot 0..7
    const int hw = lane & 1;                       // which 8-dim half of the 16-dim slice
    const unsigned short* fs = feat + (size_t)s * NN * 16;  // 3.2 MB slice, L2-resident

    const unsigned info = rsinfo[node];
    unsigned j = info >> 10;
    int rem = (int)(info & 1023u);

    h2v acc[4];
#pragma unroll
    for (int k = 0; k < 4; ++k) acc[k] = (h2v)0;

    while (__any(rem > 0)) {
        int take = rem > 16 ? 16 : (rem > 0 ? rem : 0);
        int cidx = 0;
        if ((lane & 15) < take) cidx = csr[j + (lane & 15)];  // stage 16 edges, 1 VMEM/lane
        int i0 = __shfl(cidx, n4 | slot, 64);
        int i1 = __shfl(cidx, n4 | (slot + 8), 64);
        if (slot < take) {
            u32x4 v = *reinterpret_cast<const u32x4*>(&fs[(size_t)(unsigned)i0 * 16 + hw * 8]);
#pragma unroll
            for (int k = 0; k < 4; ++k) acc[k] += bch2(v[k]);
        }
        if (slot + 8 < take) {
            u32x4 v = *reinterpret_cast<const u32x4*>(&fs[(size_t)(unsigned)i1 * 16 + hw * 8]);
#pragma unroll
            for (int k = 0; k < 4; ++k) acc[k] += bch2(v[k]);
        }
        j += take; rem -= take;
    }
    // reduce across the 8 slots (lane bits 1..3); node bits (4..5) and hw (0) untouched
#pragma unroll
    for (int k = 0; k < 4; ++k) {
        unsigned w = __builtin_bit_cast(unsigned, acc[k]);
        acc[k] += bch2((unsigned)__shfl_xor((int)w, 2, 64));
        w = __builtin_bit_cast(unsigned, acc[k]);
        acc[k] += bch2((unsigned)__shfl_xor((int)w, 4, 64));
        w = __builtin_bit_cast(unsigned, acc[k]);
        acc[k] += bch2((unsigned)__shfl_xor((int)w, 8, 64));
    }
    if (slot == 0) {
        const float si = dsin[node];
        const unsigned co = cnt_out[node];
        const float so = rsqrtf((float)(co ? co : 1u));
        const int d0 = s * 16 + hw * 8;
        const float4 bb0 = *reinterpret_cast<const float4*>(&b1[d0]);
        const float4 bb1 = *reinterpret_cast<const float4*>(&b1[d0 + 4]);
        u16x8 p;
        p[0] = f2bf(fmaxf((float)acc[0][0] * si + bb0.x, 0.f) * so);
        p[1] = f2bf(fmaxf((float)acc[0][1] * si + bb0.y, 0.f) * so);
        p[2] = f2bf(fmaxf((float)acc[1][0] * si + bb0.z, 0.f) * so);
        p[3] = f2bf(fmaxf((float)acc[1][1] * si + bb0.w, 0.f) * so);
        p[4] = f2bf(fmaxf((float)acc[2][0] * si + bb1.x, 0.f) * so);
        p[5] = f2bf(fmaxf((float)acc[2][1] * si + bb1.y, 0.f) * so);
        p[6] = f2bf(fmaxf((float)acc[3][0] * si + bb1.z, 0.f) * so);
        p[7] = f2bf(fmaxf((float)acc[3][1] * si + bb1.w, 0.f) * so);
        *reinterpret_cast<u16x8*>(&xs[((size_t)s * NN + node) * 16 + hw * 8]) = p;
    }
}

// ---- SpMM layer 2: 8-lane groups, f16 table, v_pk_add_f16 + softmax ----
__global__ __launch_bounds__(256) void spmm2_kernel(const unsigned short* __restrict__ feat2,
                                                    const int* __restrict__ csr,
                                                    const unsigned* __restrict__ rsinfo,
                                                    const float* __restrict__ dsin,
                                                    const float* __restrict__ b2,
                                                    float* __restrict__ out) {
    const int wave = threadIdx.x >> 6;
    const int lane = threadIdx.x & 63;
    const int node = blockIdx.x * 4 + wave;
    if (node >= NN) return;
    const unsigned info = rsinfo[node];
    unsigned j = info >> 10;
    int rem = (int)(info & 1023u);
    const int g = lane >> 3;        // edge subgroup 0..7
    const int c8 = (lane & 7) * 8;  // 8-dim slice
    h2v acch[4];
#pragma unroll
    for (int i = 0; i < 4; ++i) acch[i] = (h2v)0;
    while (rem > 0) {
        const int take = rem < 64 ? rem : 64;
        const int idx = (lane < take) ? csr[j + lane] : 0;
        int e = 0;
        for (; e + 32 <= take; e += 32) {  // 32 edges, 4 loads in flight
            int s0 = __shfl(idx, e + g, 64);
            int s1 = __shfl(idx, e + 8 + g, 64);
            int s2 = __shfl(idx, e + 16 + g, 64);
            int s3 = __shfl(idx, e + 24 + g, 64);
            u32x4 v0 = *reinterpret_cast<const u32x4*>(&feat2[(size_t)s0 * OUT_DIM + c8]);
            u32x4 v1 = *reinterpret_cast<const u32x4*>(&feat2[(size_t)s1 * OUT_DIM + c8]);
            u32x4 v2 = *reinterpret_cast<const u32x4*>(&feat2[(size_t)s2 * OUT_DIM + c8]);
            u32x4 v3 = *reinterpret_cast<const u32x4*>(&feat2[(size_t)s3 * OUT_DIM + c8]);
#pragma unroll
            for (int k = 0; k < 4; ++k) {
                h2v t0 = bch2(v0[k]) + bch2(v1[k]);
                h2v t1 = bch2(v2[k]) + bch2(v3[k]);
                acch[k] += t0 + t1;
            }
        }
        for (; e + 16 <= take; e += 16) {  // 16 edges, 2 loads in flight (common deg~16)
            int s0 = __shfl(idx, e + g, 64);
            int s1 = __shfl(idx, e + 8 + g, 64);
            u32x4 v0 = *reinterpret_cast<const u32x4*>(&feat2[(size_t)s0 * OUT_DIM + c8]);
            u32x4 v1 = *reinterpret_cast<const u32x4*>(&feat2[(size_t)s1 * OUT_DIM + c8]);
#pragma unroll
            for (int k = 0; k < 4; ++k) acch[k] += bch2(v0[k]) + bch2(v1[k]);
        }
        for (; e + 8 <= take; e += 8) {    // 8 edges, 1 load
            int s0 = __shfl(idx, e + g, 64);
            u32x4 v0 = *reinterpret_cast<const u32x4*>(&feat2[(size_t)s0 * OUT_DIM + c8]);
#pragma unroll
            for (int k = 0; k < 4; ++k) acch[k] += bch2(v0[k]);
        }
        if (e < take) {                    // masked tail (1..7 edges)
            int ei = e + g;
            int sl = ei < take ? ei : take - 1;
            int s0 = __shfl(idx, sl, 64);
            u32x4 v0 = *reinterpret_cast<const u32x4*>(&feat2[(size_t)s0 * OUT_DIM + c8]);
            if (ei < take) {
#pragma unroll
                for (int k = 0; k < 4; ++k) acch[k] += bch2(v0[k]);
            }
        }
        j += take; rem -= take;
    }
    // combine the 8 edge subgroups (packed shuffles)
#pragma unroll
    for (int k = 0; k < 4; ++k) {
        unsigned w = __builtin_bit_cast(unsigned, acch[k]);
        acch[k] += bch2((unsigned)__shfl_xor((int)w, 8, 64));
        w = __builtin_bit_cast(unsigned, acch[k]);
        acch[k] += bch2((unsigned)__shfl_xor((int)w, 16, 64));
        w = __builtin_bit_cast(unsigned, acch[k]);
        acch[k] += bch2((unsigned)__shfl_xor((int)w, 32, 64));
    }
    const float si = dsin[node];
    const float4 bb0 = *reinterpret_cast<const float4*>(&b2[c8]);
    const float4 bb1 = *reinterpret_cast<const float4*>(&b2[c8 + 4]);
    const float bv[8] = {bb0.x, bb0.y, bb0.z, bb0.w, bb1.x, bb1.y, bb1.z, bb1.w};
    float l[8];
#pragma unroll
    for (int k = 0; k < 4; ++k) {
        l[2 * k] = (float)acch[k][0] * si + bv[2 * k];
        l[2 * k + 1] = (float)acch[k][1] * si + bv[2 * k + 1];
    }
    float m = l[0];
#pragma unroll
    for (int i = 1; i < 8; ++i) m = fmaxf(m, l[i]);
    m = fmaxf(m, __shfl_xor(m, 1, 64));
    m = fmaxf(m, __shfl_xor(m, 2, 64));
    m = fmaxf(m, __shfl_xor(m, 4, 64));
    float ee[8];
    float s = 0.f;
#pragma unroll
    for (int i = 0; i < 8; ++i) { ee[i] = __expf(l[i] - m); s += ee[i]; }
    s += __shfl_xor(s, 1, 64);
    s += __shfl_xor(s, 2, 64);
    s += __shfl_xor(s, 4, 64);
    const float inv = 1.0f / s;
    if (lane < 8) {
        float4 p0 = make_float4(ee[0] * inv, ee[1] * inv, ee[2] * inv, ee[3] * inv);
        float4 p1 = make_float4(ee[4] * inv, ee[5] * inv, ee[6] * inv, ee[7] * inv);
        *reinterpret_cast<float4*>(&out[(size_t)node * OUT_DIM + c8]) = p0;
        *reinterpret_cast<float4*>(&out[(size_t)node * OUT_DIM + c8 + 4]) = p1;
        float4 q0 = make_float4(l[0], l[1], l[2], l[3]);
        float4 q1 = make_float4(l[4], l[5], l[6], l[7]);
        float* lg = &out[(size_t)NN * OUT_DIM + (size_t)node * OUT_DIM + c8];
        *reinterpret_cast<float4*>(lg) = q0;
        *reinterpret_cast<float4*>(lg + 4) = q1;
    }
}

static inline size_t align_up(size_t x, size_t a) { return (x + a - 1) & ~(a - 1); }

extern "C" void kernel_launch(void* const* d_in, const int* in_sizes, int n_in,
                              void* d_out, int out_size, void* d_ws, size_t ws_size,
                              hipStream_t stream) {
    (void)in_sizes; (void)n_in; (void)out_size;
    const float* h = (const float*)d_in[0];
    const float* W1 = (const float*)d_in[1];
    const float* b1 = (const float*)d_in[2];
    const float* W2 = (const float*)d_in[3];
    const float* b2 = (const float*)d_in[4];
    const int* src = (const int*)d_in[5];
    const int* dst = (const int*)d_in[6];
    float* out = (float*)d_out;

    char* ws = (char*)d_ws;
    size_t off = 0;
    auto alloc = [&](size_t bytes) {
        void* p = (void*)(ws + off);
        off = align_up(off + bytes, 512);
        return p;
    };
    unsigned* cnt_out = (unsigned*)alloc(NN * 4);
    unsigned short* cnt2dD = (unsigned short*)alloc((size_t)NBLK * NFB * 2);
    unsigned short* cnt2dS = (unsigned short*)alloc((size_t)NBLK * NFB * 2);
    unsigned* btotD = (unsigned*)alloc(NFB * 4);
    unsigned* btotS = (unsigned*)alloc(NFB * 4);
    unsigned* rsinfo = (unsigned*)alloc(NN * 4);
    float* dsin = (float*)alloc(NN * 4);
    unsigned* ebufD = (unsigned*)alloc((size_t)NFB * CAP * 4);
    unsigned char* ebufS = (unsigned char*)alloc((size_t)NFB * CAP);
    int* csr = (int*)alloc((size_t)NFB * CAP * 4);
    unsigned short* W1t = (unsigned short*)alloc((size_t)HID_DIM * IN_DIM * 2);
    unsigned short* W2t = (unsigned short*)alloc((size_t)OUT_DIM * HID_DIM * 2);
    unsigned short* feat1 = (unsigned short*)alloc((size_t)NN * HID_DIM * 2);  // slice-major
    unsigned short* xs = (unsigned short*)alloc((size_t)NN * HID_DIM * 2);     // slice-major
    unsigned short* feat2 = feat1;  // alias: feat1 dead after spmm1

    if (off > ws_size) {
        fprintf(stderr, "kernel_launch: ws too small: need %zu, have %zu\n", off, ws_size);
        return;
    }

    scat1_kernel<<<NBLK, 256, 0, stream>>>(src, dst, cnt2dD, cnt2dS);
    scanCprep_kernel<<<2 * NFB + PREP_BLKS, 128, 0, stream>>>(cnt2dD, cnt2dS, btotD, btotS,
                                                              W1, W2, W1t, W2t);
    scat2_kernel<<<NBLK, 256, 0, stream>>>(src, dst, cnt2dD, cnt2dS, ebufD, ebufS);
    bsortc_kernel<<<NFB, 256, 0, stream>>>(ebufD, btotD, ebufS, btotS, csr, rsinfo, dsin,
                                           cnt_out);

    gemm1_kernel<<<(NN + 127) / 128, 256, 0, stream>>>(h, W1t, cnt_out, feat1, NN);
    spmm1_kernel<<<8 * (NN / 16), 256, 0, stream>>>(feat1, csr, rsinfo, dsin, cnt_out, b1, xs);
    gemm2_kernel<<<(NN + 127) / 128, 256, 0, stream>>>(xs, W2t, feat2, NN);
    spmm2_kernel<<<(NN + 3) / 4, 256, 0, stream>>>(feat2, csr, rsinfo, dsin, b2, out);
}

// Round 16
// 207.468 us; speedup vs baseline: 1.1179x; 1.1179x over previous
//
#include <hip/hip_runtime.h>
#include <cstdio>

#define NN 100000
#define NE 1600000
#define IN_DIM 256
#define HID_DIM 128
#define OUT_DIM 64

#define EPB 4096                         // edges per scat block
#define NBLK ((NE + EPB - 1) / EPB)      // 391
#define FBSH 7
#define FBN 128                          // nodes per fine bucket
#define NFB 782                          // ceil(NN/128)
#define CAP 2560                         // per-bucket capacity (mean 2048, +11 sigma)
#define PREP_ELEMS (HID_DIM * IN_DIM + OUT_DIM * HID_DIM)  // 40960
#define PREP_BLKS ((PREP_ELEMS + 127) / 128)               // 320

typedef short s8v __attribute__((ext_vector_type(8)));
typedef float f4v __attribute__((ext_vector_type(4)));
typedef _Float16 h2v __attribute__((ext_vector_type(2)));
typedef unsigned u32x4 __attribute__((ext_vector_type(4)));
typedef unsigned short u16x4 __attribute__((ext_vector_type(4)));
typedef unsigned short u16x8 __attribute__((ext_vector_type(8)));
typedef int i32x4 __attribute__((ext_vector_type(4)));

__device__ __forceinline__ unsigned short f2bf(float f) {
    unsigned u = __builtin_bit_cast(unsigned, f);
    u += 0x7FFFu + ((u >> 16) & 1u);  // RNE
    return (unsigned short)(u >> 16);
}
__device__ __forceinline__ unsigned short f2h(float f) {
    return __builtin_bit_cast(unsigned short, (_Float16)f);
}
__device__ __forceinline__ h2v bch2(unsigned w) { return __builtin_bit_cast(h2v, w); }

// ---------------- scat1: per-(block,bucket) counts for dst and src (int4 loads) ----------
__global__ __launch_bounds__(256) void scat1_kernel(const int* __restrict__ src,
                                                    const int* __restrict__ dst,
                                                    unsigned short* __restrict__ cnt2dD,
                                                    unsigned short* __restrict__ cnt2dS) {
    __shared__ unsigned hbD[NFB], hbS[NFB];
    const int t = threadIdx.x;
    for (int i = t; i < NFB; i += 256) { hbD[i] = 0u; hbS[i] = 0u; }
    __syncthreads();
    const int base = blockIdx.x * EPB;
    int n = NE - base; if (n > EPB) n = EPB;
    const i32x4* d4 = reinterpret_cast<const i32x4*>(dst + base);
    const i32x4* s4 = reinterpret_cast<const i32x4*>(src + base);
    const int nq = n >> 2;
    for (int i = t; i < nq; i += 256) {
        i32x4 d = d4[i];
        i32x4 s = s4[i];
#pragma unroll
        for (int k = 0; k < 4; ++k) {
            atomicAdd(&hbD[(unsigned)d[k] >> FBSH], 1u);
            atomicAdd(&hbS[(unsigned)s[k] >> FBSH], 1u);
        }
    }
    for (int i = (nq << 2) + t; i < n; i += 256) {
        atomicAdd(&hbD[dst[base + i] >> FBSH], 1u);
        atomicAdd(&hbS[src[base + i] >> FBSH], 1u);
    }
    __syncthreads();
    const size_t row = (size_t)blockIdx.x * NFB;
    for (int i = t; i < NFB; i += 256) {
        cnt2dD[row + i] = (unsigned short)hbD[i];
        cnt2dS[row + i] = (unsigned short)hbS[i];
    }
}

// ---- scanC + weight prep fused ----
__global__ __launch_bounds__(128) void scanCprep_kernel(unsigned short* __restrict__ cnt2dD,
                                                        unsigned short* __restrict__ cnt2dS,
                                                        unsigned* __restrict__ btotD,
                                                        unsigned* __restrict__ btotS,
                                                        const float* __restrict__ W1,
                                                        const float* __restrict__ W2,
                                                        unsigned short* __restrict__ W1t,
                                                        unsigned short* __restrict__ W2t) {
    const int g = blockIdx.x;
    if (g >= 2 * NFB) {  // weight prep path (bf16 transpose)
        int i = (g - 2 * NFB) * 128 + threadIdx.x;
        if (i < HID_DIM * IN_DIM) {
            int n = i >> 8, k = i & 255;
            W1t[i] = f2bf(W1[k * HID_DIM + n]);
        } else if (i < PREP_ELEMS) {
            int m = i - HID_DIM * IN_DIM;
            int n = m >> 7, k = m & 127;
            W2t[m] = f2bf(W2[k * OUT_DIM + n]);
        }
        return;
    }
    __shared__ unsigned sc[128];
    unsigned short* arr = (g < NFB) ? cnt2dD : cnt2dS;
    unsigned* btot = (g < NFB) ? btotD : btotS;
    const int b = (g < NFB) ? g : g - NFB;
    const int t = threadIdx.x;
    unsigned v[4];
    unsigned s = 0;
#pragma unroll
    for (int i = 0; i < 4; ++i) {
        int blk = t * 4 + i;
        unsigned x = (blk < NBLK) ? (unsigned)arr[(size_t)blk * NFB + b] : 0u;
        v[i] = s;
        s += x;
    }
    sc[t] = s;
    __syncthreads();
    for (int o = 1; o < 128; o <<= 1) {
        unsigned add = (t >= o) ? sc[t - o] : 0u;
        __syncthreads();
        sc[t] += add;
        __syncthreads();
    }
    unsigned incl = sc[t];
    unsigned excl = incl - s;
#pragma unroll
    for (int i = 0; i < 4; ++i) {
        int blk = t * 4 + i;
        if (blk < NBLK) arr[(size_t)blk * NFB + b] = (unsigned short)(excl + v[i]);
    }
    if (t == 127) btot[b] = incl;
}

// ---------------- scat2: scatter into CAP-strided bucket regions (int4 loads) ------------
__global__ __launch_bounds__(256) void scat2_kernel(const int* __restrict__ src,
                                                    const int* __restrict__ dst,
                                                    const unsigned short* __restrict__ ofsD,
                                                    const unsigned short* __restrict__ ofsS,
                                                    unsigned* __restrict__ ebufD,
                                                    unsigned char* __restrict__ ebufS) {
    __shared__ unsigned curD[NFB], curS[NFB];
    const int t = threadIdx.x;
    const size_t row = (size_t)blockIdx.x * NFB;
    for (int i = t; i < NFB; i += 256) {
        curD[i] = (unsigned)i * CAP + (unsigned)ofsD[row + i];
        curS[i] = (unsigned)i * CAP + (unsigned)ofsS[row + i];
    }
    __syncthreads();
    const int base = blockIdx.x * EPB;
    int n = NE - base; if (n > EPB) n = EPB;
    const i32x4* d4 = reinterpret_cast<const i32x4*>(dst + base);
    const i32x4* s4 = reinterpret_cast<const i32x4*>(src + base);
    const int nq = n >> 2;
    for (int i = t; i < nq; i += 256) {
        i32x4 d = d4[i];
        i32x4 s = s4[i];
#pragma unroll
        for (int k = 0; k < 4; ++k) {
            unsigned pD = atomicAdd(&curD[(unsigned)d[k] >> FBSH], 1u);
            ebufD[pD] = ((unsigned)(d[k] & 127) << 17) | (unsigned)s[k];
            unsigned pS = atomicAdd(&curS[(unsigned)s[k] >> FBSH], 1u);
            ebufS[pS] = (unsigned char)(s[k] & 127);
        }
    }
    for (int i = (nq << 2) + t; i < n; i += 256) {
        int d = dst[base + i];
        int s = src[base + i];
        unsigned pD = atomicAdd(&curD[d >> FBSH], 1u);
        ebufD[pD] = ((unsigned)(d & 127) << 17) | (unsigned)s;
        unsigned pS = atomicAdd(&curS[s >> FBSH], 1u);
        ebufS[pS] = (unsigned char)(s & 127);
    }
}

// ---- bsort + countB fused (u32x4 edge loads, 4-tag u32 loads) ----
__global__ __launch_bounds__(256) void bsortc_kernel(const unsigned* __restrict__ ebufD,
                                                     const unsigned* __restrict__ btotD,
                                                     const unsigned char* __restrict__ ebufS,
                                                     const unsigned* __restrict__ btotS,
                                                     int* __restrict__ csr,
                                                     unsigned* __restrict__ rsinfo,
                                                     float* __restrict__ dsin,
                                                     unsigned* __restrict__ cnt_out) {
    __shared__ unsigned hn[FBN];
    __shared__ unsigned sc[FBN];
    __shared__ unsigned cur[FBN];
    const int b = blockIdx.x;
    const int t = threadIdx.x;
    const unsigned e0 = (unsigned)b * CAP;
    const unsigned nD = btotD[b];
    if (t < FBN) hn[t] = 0u;
    __syncthreads();
    const u32x4* eD4 = reinterpret_cast<const u32x4*>(ebufD + e0);
    const int nDq = (int)(nD >> 2);
    for (int i = t; i < nDq; i += 256) {
        u32x4 v = eD4[i];
#pragma unroll
        for (int k = 0; k < 4; ++k) atomicAdd(&hn[(v[k] >> 17) & 127u], 1u);
    }
    for (unsigned j = (unsigned)(nDq << 2) + t; j < nD; j += 256)
        atomicAdd(&hn[(ebufD[e0 + j] >> 17) & 127u], 1u);
    __syncthreads();
    unsigned cnt_t = (t < FBN) ? hn[t] : 0u;
    if (t < FBN) sc[t] = cnt_t;
    __syncthreads();
    for (int o = 1; o < FBN; o <<= 1) {
        unsigned add = (t < FBN && t >= o) ? sc[t - o] : 0u;
        __syncthreads();
        if (t < FBN) sc[t] += add;
        __syncthreads();
    }
    if (t < FBN) {
        unsigned excl = sc[t] - cnt_t;
        cur[t] = e0 + excl;
        int node = (b << FBSH) + t;
        if (node < NN) {
            rsinfo[node] = ((e0 + excl) << 10) | (cnt_t & 1023u);
            dsin[node] = rsqrtf((float)(cnt_t ? cnt_t : 1u));
        }
    }
    __syncthreads();
    for (int i = t; i < nDq; i += 256) {
        u32x4 v = eD4[i];
#pragma unroll
        for (int k = 0; k < 4; ++k) {
            unsigned pos = atomicAdd(&cur[(v[k] >> 17) & 127u], 1u);
            csr[pos] = (int)(v[k] & 0x1FFFFu);
        }
    }
    for (unsigned j = (unsigned)(nDq << 2) + t; j < nD; j += 256) {
        unsigned pk = ebufD[e0 + j];
        unsigned pos = atomicAdd(&cur[(pk >> 17) & 127u], 1u);
        csr[pos] = (int)(pk & 0x1FFFFu);
    }
    // ---- phase 2: src-tag histogram -> cnt_out ----
    __syncthreads();
    if (t < FBN) hn[t] = 0u;
    __syncthreads();
    const unsigned nS = btotS[b];
    const unsigned* eS4 = reinterpret_cast<const unsigned*>(ebufS + e0);
    const int nSq = (int)(nS >> 2);
    for (int i = t; i < nSq; i += 256) {
        unsigned w = eS4[i];
        atomicAdd(&hn[w & 127u], 1u);
        atomicAdd(&hn[(w >> 8) & 127u], 1u);
        atomicAdd(&hn[(w >> 16) & 127u], 1u);
        atomicAdd(&hn[(w >> 24) & 127u], 1u);
    }
    for (unsigned j = (unsigned)(nSq << 2) + t; j < nS; j += 256)
        atomicAdd(&hn[ebufS[e0 + j]], 1u);
    __syncthreads();
    if (t < FBN) {
        int node = (b << FBSH) + t;
        if (node < NN) cnt_out[node] = hn[t];
    }
}

// ---- GEMM1 (MFMA bf16, pipelined): feat1[M,128] (f16) = ((h @ W1) .* dsout_row) ----
__global__ __launch_bounds__(256) void gemm1_kernel(const float* __restrict__ h,
                                                    const unsigned short* __restrict__ W1t,
                                                    const unsigned* __restrict__ cnt_out,
                                                    unsigned short* __restrict__ feat1, int M) {
    __shared__ unsigned short sA[2][128][40];  // 80B row stride, 16B aligned
    const int tid = threadIdx.x;
    const int lane = tid & 63;
    const int wave = tid >> 6;
    const int wm = wave >> 1, wn = wave & 1;
    const int m0 = blockIdx.x * 128;
    const int arow = tid >> 3;   // 0..31
    const int akq = tid & 7;     // float4 within 32 k

    f4v acc[4][4];
#pragma unroll
    for (int i = 0; i < 4; ++i)
#pragma unroll
        for (int j = 0; j < 4; ++j) acc[i][j] = (f4v)0.f;

    int mrow[4]; bool mok[4];
#pragma unroll
    for (int i = 0; i < 4; ++i) { mrow[i] = m0 + arow + i * 32; mok[i] = mrow[i] < M; }

    float4 pre[4];
#pragma unroll
    for (int i = 0; i < 4; ++i)
        pre[i] = mok[i] ? *reinterpret_cast<const float4*>(&h[(size_t)mrow[i] * IN_DIM + akq * 4])
                        : make_float4(0.f, 0.f, 0.f, 0.f);
#pragma unroll
    for (int i = 0; i < 4; ++i) {
        u16x4 p;
        p[0] = f2bf(pre[i].x); p[1] = f2bf(pre[i].y);
        p[2] = f2bf(pre[i].z); p[3] = f2bf(pre[i].w);
        *reinterpret_cast<u16x4*>(&sA[0][arow + i * 32][akq * 4]) = p;
    }
    __syncthreads();

    int cur = 0;
#pragma unroll
    for (int ks = 0; ks < 8; ++ks) {
        if (ks < 7) {
            const int k0n = (ks + 1) * 32;
#pragma unroll
            for (int i = 0; i < 4; ++i)
                pre[i] = mok[i] ? *reinterpret_cast<const float4*>(
                                      &h[(size_t)mrow[i] * IN_DIM + k0n + akq * 4])
                                : make_float4(0.f, 0.f, 0.f, 0.f);
        }
        s8v bfrag[4];
#pragma unroll
        for (int ni = 0; ni < 4; ++ni)
            bfrag[ni] = *reinterpret_cast<const s8v*>(
                &W1t[(size_t)(wn * 64 + ni * 16 + (lane & 15)) * IN_DIM + ks * 32 + (lane >> 4) * 8]);
        s8v afrag[4];
#pragma unroll
        for (int mi = 0; mi < 4; ++mi)
            afrag[mi] = *reinterpret_cast<const s8v*>(
                &sA[cur][wm * 64 + mi * 16 + (lane & 15)][(lane >> 4) * 8]);
#pragma unroll
        for (int ni = 0; ni < 4; ++ni)
#pragma unroll
            for (int mi = 0; mi < 4; ++mi)
                acc[mi][ni] = __builtin_amdgcn_mfma_f32_16x16x32_bf16(afrag[mi], bfrag[ni], acc[mi][ni], 0, 0, 0);
        if (ks < 7) {
#pragma unroll
            for (int i = 0; i < 4; ++i) {
                u16x4 p;
                p[0] = f2bf(pre[i].x); p[1] = f2bf(pre[i].y);
                p[2] = f2bf(pre[i].z); p[3] = f2bf(pre[i].w);
                *reinterpret_cast<u16x4*>(&sA[cur ^ 1][arow + i * 32][akq * 4]) = p;
            }
        }
        __syncthreads();
        cur ^= 1;
    }
    // epilogue: per-row dsout scale + f16 store
#pragma unroll
    for (int mi = 0; mi < 4; ++mi) {
#pragma unroll
        for (int j = 0; j < 4; ++j) {
            int row = m0 + wm * 64 + mi * 16 + (lane >> 4) * 4 + j;
            if (row < M) {
                unsigned cdeg = cnt_out[row];
                float s = rsqrtf((float)(cdeg ? cdeg : 1u));
#pragma unroll
                for (int ni = 0; ni < 4; ++ni) {
                    int col = wn * 64 + ni * 16 + (lane & 15);
                    feat1[(size_t)row * HID_DIM + col] = f2h(acc[mi][ni][j] * s);
                }
            }
        }
    }
}

// ---- GEMM2 (MFMA bf16, pipelined): feat2[M,64] (f16) = xs @ W2 ----
__global__ __launch_bounds__(256) void gemm2_kernel(const unsigned short* __restrict__ xs,
                                                    const unsigned short* __restrict__ W2t,
                                                    unsigned short* __restrict__ feat2, int M) {
    __shared__ unsigned short sA[2][128][40];
    const int tid = threadIdx.x;
    const int lane = tid & 63;
    const int wave = tid >> 6;
    const int wm = wave >> 1, wn = wave & 1;
    const int m0 = blockIdx.x * 128;

    f4v acc[4][2];
#pragma unroll
    for (int i = 0; i < 4; ++i)
#pragma unroll
        for (int j = 0; j < 2; ++j) acc[i][j] = (f4v)0.f;

    int srow[2], skq[2]; bool sok[2];
#pragma unroll
    for (int i = 0; i < 2; ++i) {
        int idx = tid + i * 256;
        srow[i] = idx >> 2; skq[i] = idx & 3;
        sok[i] = (m0 + srow[i]) < M;
    }

    u16x8 pre[2];
#pragma unroll
    for (int i = 0; i < 2; ++i)
        pre[i] = sok[i] ? *reinterpret_cast<const u16x8*>(
                              &xs[(size_t)(m0 + srow[i]) * HID_DIM + skq[i] * 8])
                        : (u16x8)0;
#pragma unroll
    for (int i = 0; i < 2; ++i)
        *reinterpret_cast<u16x8*>(&sA[0][srow[i]][skq[i] * 8]) = pre[i];
    __syncthreads();

    int cur = 0;
#pragma unroll
    for (int ks = 0; ks < 4; ++ks) {
        if (ks < 3) {
            const int k0n = (ks + 1) * 32;
#pragma unroll
            for (int i = 0; i < 2; ++i)
                pre[i] = sok[i] ? *reinterpret_cast<const u16x8*>(
                                      &xs[(size_t)(m0 + srow[i]) * HID_DIM + k0n + skq[i] * 8])
                                : (u16x8)0;
        }
        s8v bfrag[2];
#pragma unroll
        for (int ni = 0; ni < 2; ++ni)
            bfrag[ni] = *reinterpret_cast<const s8v*>(
                &W2t[(size_t)(wn * 32 + ni * 16 + (lane & 15)) * HID_DIM + ks * 32 + (lane >> 4) * 8]);
        s8v afrag[4];
#pragma unroll
        for (int mi = 0; mi < 4; ++mi)
            afrag[mi] = *reinterpret_cast<const s8v*>(
                &sA[cur][wm * 64 + mi * 16 + (lane & 15)][(lane >> 4) * 8]);
#pragma unroll
        for (int ni = 0; ni < 2; ++ni)
#pragma unroll
            for (int mi = 0; mi < 4; ++mi)
                acc[mi][ni] = __builtin_amdgcn_mfma_f32_16x16x32_bf16(afrag[mi], bfrag[ni], acc[mi][ni], 0, 0, 0);
        if (ks < 3) {
#pragma unroll
            for (int i = 0; i < 2; ++i)
                *reinterpret_cast<u16x8*>(&sA[cur ^ 1][srow[i]][skq[i] * 8]) = pre[i];
        }
        __syncthreads();
        cur ^= 1;
    }
#pragma unroll
    for (int mi = 0; mi < 4; ++mi)
#pragma unroll
        for (int ni = 0; ni < 2; ++ni) {
            int col = wn * 32 + ni * 16 + (lane & 15);
#pragma unroll
            for (int j = 0; j < 4; ++j) {
                int row = m0 + wm * 64 + mi * 16 + (lane >> 4) * 4 + j;
                if (row < M) feat2[(size_t)row * OUT_DIM + col] = f2h(acc[mi][ni][j]);
            }
        }
}

// ---- SpMM layer 1: 16-lane groups, f16 table, v_pk_add_f16 accumulate ----
__global__ __launch_bounds__(256) void spmm1_kernel(const unsigned short* __restrict__ feat,
                                                    const int* __restrict__ csr,
                                                    const unsigned* __restrict__ rsinfo,
                                                    const float* __restrict__ dsin,
                                                    const unsigned* __restrict__ cnt_out,
                                                    const float* __restrict__ b1,
                                                    unsigned short* __restrict__ xs) {
    const int wave = threadIdx.x >> 6;
    const int lane = threadIdx.x & 63;
    const int node = blockIdx.x * 4 + wave;
    if (node >= NN) return;
    const unsigned info = rsinfo[node];
    unsigned j = info >> 10;
    int rem = (int)(info & 1023u);
    const int g = lane >> 4;        // edge subgroup 0..3
    const int c8 = (lane & 15) * 8; // 8-dim slice
    h2v acch[4];
#pragma unroll
    for (int i = 0; i < 4; ++i) acch[i] = (h2v)0;
    while (rem > 0) {
        const int take = rem < 64 ? rem : 64;
        const int idx = (lane < take) ? csr[j + lane] : 0;
        int e = 0;
        for (; e + 16 <= take; e += 16) {  // 16 edges, 4 loads in flight
            int s0 = __shfl(idx, e + g, 64);
            int s1 = __shfl(idx, e + 4 + g, 64);
            int s2 = __shfl(idx, e + 8 + g, 64);
            int s3 = __shfl(idx, e + 12 + g, 64);
            u32x4 v0 = *reinterpret_cast<const u32x4*>(&feat[(size_t)s0 * HID_DIM + c8]);
            u32x4 v1 = *reinterpret_cast<const u32x4*>(&feat[(size_t)s1 * HID_DIM + c8]);
            u32x4 v2 = *reinterpret_cast<const u32x4*>(&feat[(size_t)s2 * HID_DIM + c8]);
            u32x4 v3 = *reinterpret_cast<const u32x4*>(&feat[(size_t)s3 * HID_DIM + c8]);
#pragma unroll
            for (int k = 0; k < 4; ++k) {
                h2v t0 = bch2(v0[k]) + bch2(v1[k]);
                h2v t1 = bch2(v2[k]) + bch2(v3[k]);
                acch[k] += t0 + t1;
            }
        }
        for (; e + 4 <= take; e += 4) {    // 4 edges, 1 load
            int s0 = __shfl(idx, e + g, 64);
            u32x4 v0 = *reinterpret_cast<const u32x4*>(&feat[(size_t)s0 * HID_DIM + c8]);
#pragma unroll
            for (int k = 0; k < 4; ++k) acch[k] += bch2(v0[k]);
        }
        if (e < take) {                    // masked tail (1..3 edges)
            int ei = e + g;
            int sl = ei < take ? ei : take - 1;
            int s0 = __shfl(idx, sl, 64);
            u32x4 v0 = *reinterpret_cast<const u32x4*>(&feat[(size_t)s0 * HID_DIM + c8]);
            if (ei < take) {
#pragma unroll
                for (int k = 0; k < 4; ++k) acch[k] += bch2(v0[k]);
            }
        }
        j += take; rem -= take;
    }
    // combine the 4 edge subgroups (packed shuffles)
#pragma unroll
    for (int k = 0; k < 4; ++k) {
        unsigned w = __builtin_bit_cast(unsigned, acch[k]);
        acch[k] += bch2((unsigned)__shfl_xor((int)w, 16, 64));
        w = __builtin_bit_cast(unsigned, acch[k]);
        acch[k] += bch2((unsigned)__shfl_xor((int)w, 32, 64));
    }
    if (g == 0) {
        const float si = dsin[node];
        const unsigned co = cnt_out[node];
        const float so = rsqrtf((float)(co ? co : 1u));
        const float4 bb0 = *reinterpret_cast<const float4*>(&b1[c8]);
        const float4 bb1 = *reinterpret_cast<const float4*>(&b1[c8 + 4]);
        const float bv[8] = {bb0.x, bb0.y, bb0.z, bb0.w, bb1.x, bb1.y, bb1.z, bb1.w};
        u16x8 p;
#pragma unroll
        for (int k = 0; k < 4; ++k) {
            p[2 * k] = f2bf(fmaxf((float)acch[k][0] * si + bv[2 * k], 0.f) * so);
            p[2 * k + 1] = f2bf(fmaxf((float)acch[k][1] * si + bv[2 * k + 1], 0.f) * so);
        }
        *reinterpret_cast<u16x8*>(&xs[(size_t)node * HID_DIM + c8]) = p;
    }
}

// ---- SpMM layer 2: 8-lane groups, f16 table, v_pk_add_f16 + softmax ----
__global__ __launch_bounds__(256) void spmm2_kernel(const unsigned short* __restrict__ feat2,
                                                    const int* __restrict__ csr,
                                                    const unsigned* __restrict__ rsinfo,
                                                    const float* __restrict__ dsin,
                                                    const float* __restrict__ b2,
                                                    float* __restrict__ out) {
    const int wave = threadIdx.x >> 6;
    const int lane = threadIdx.x & 63;
    const int node = blockIdx.x * 4 + wave;
    if (node >= NN) return;
    const unsigned info = rsinfo[node];
    unsigned j = info >> 10;
    int rem = (int)(info & 1023u);
    const int g = lane >> 3;        // edge subgroup 0..7
    const int c8 = (lane & 7) * 8;  // 8-dim slice
    h2v acch[4];
#pragma unroll
    for (int i = 0; i < 4; ++i) acch[i] = (h2v)0;
    while (rem > 0) {
        const int take = rem < 64 ? rem : 64;
        const int idx = (lane < take) ? csr[j + lane] : 0;
        int e = 0;
        for (; e + 32 <= take; e += 32) {  // 32 edges, 4 loads in flight
            int s0 = __shfl(idx, e + g, 64);
            int s1 = __shfl(idx, e + 8 + g, 64);
            int s2 = __shfl(idx, e + 16 + g, 64);
            int s3 = __shfl(idx, e + 24 + g, 64);
            u32x4 v0 = *reinterpret_cast<const u32x4*>(&feat2[(size_t)s0 * OUT_DIM + c8]);
            u32x4 v1 = *reinterpret_cast<const u32x4*>(&feat2[(size_t)s1 * OUT_DIM + c8]);
            u32x4 v2 = *reinterpret_cast<const u32x4*>(&feat2[(size_t)s2 * OUT_DIM + c8]);
            u32x4 v3 = *reinterpret_cast<const u32x4*>(&feat2[(size_t)s3 * OUT_DIM + c8]);
#pragma unroll
            for (int k = 0; k < 4; ++k) {
                h2v t0 = bch2(v0[k]) + bch2(v1[k]);
                h2v t1 = bch2(v2[k]) + bch2(v3[k]);
                acch[k] += t0 + t1;
            }
        }
        for (; e + 16 <= take; e += 16) {  // 16 edges, 2 loads in flight (common deg~16)
            int s0 = __shfl(idx, e + g, 64);
            int s1 = __shfl(idx, e + 8 + g, 64);
            u32x4 v0 = *reinterpret_cast<const u32x4*>(&feat2[(size_t)s0 * OUT_DIM + c8]);
            u32x4 v1 = *reinterpret_cast<const u32x4*>(&feat2[(size_t)s1 * OUT_DIM + c8]);
#pragma unroll
            for (int k = 0; k < 4; ++k) acch[k] += bch2(v0[k]) + bch2(v1[k]);
        }
        for (; e + 8 <= take; e += 8) {    // 8 edges, 1 load
            int s0 = __shfl(idx, e + g, 64);
            u32x4 v0 = *reinterpret_cast<const u32x4*>(&feat2[(size_t)s0 * OUT_DIM + c8]);
#pragma unroll
            for (int k = 0; k < 4; ++k) acch[k] += bch2(v0[k]);
        }
        if (e < take) {                    // masked tail (1..7 edges)
            int ei = e + g;
            int sl = ei < take ? ei : take - 1;
            int s0 = __shfl(idx, sl, 64);
            u32x4 v0 = *reinterpret_cast<const u32x4*>(&feat2[(size_t)s0 * OUT_DIM + c8]);
            if (ei < take) {
#pragma unroll
                for (int k = 0; k < 4; ++k) acch[k] += bch2(v0[k]);
            }
        }
        j += take; rem -= take;
    }
    // combine the 8 edge subgroups (packed shuffles)
#pragma unroll
    for (int k = 0; k < 4; ++k) {
        unsigned w = __builtin_bit_cast(unsigned, acch[k]);
        acch[k] += bch2((unsigned)__shfl_xor((int)w, 8, 64));
        w = __builtin_bit_cast(unsigned, acch[k]);
        acch[k] += bch2((unsigned)__shfl_xor((int)w, 16, 64));
        w = __builtin_bit_cast(unsigned, acch[k]);
        acch[k] += bch2((unsigned)__shfl_xor((int)w, 32, 64));
    }
    const float si = dsin[node];
    const float4 bb0 = *reinterpret_cast<const float4*>(&b2[c8]);
    const float4 bb1 = *reinterpret_cast<const float4*>(&b2[c8 + 4]);
    const float bv[8] = {bb0.x, bb0.y, bb0.z, bb0.w, bb1.x, bb1.y, bb1.z, bb1.w};
    float l[8];
#pragma unroll
    for (int k = 0; k < 4; ++k) {
        l[2 * k] = (float)acch[k][0] * si + bv[2 * k];
        l[2 * k + 1] = (float)acch[k][1] * si + bv[2 * k + 1];
    }
    float m = l[0];
#pragma unroll
    for (int i = 1; i < 8; ++i) m = fmaxf(m, l[i]);
    m = fmaxf(m, __shfl_xor(m, 1, 64));
    m = fmaxf(m, __shfl_xor(m, 2, 64));
    m = fmaxf(m, __shfl_xor(m, 4, 64));
    float ee[8];
    float s = 0.f;
#pragma unroll
    for (int i = 0; i < 8; ++i) { ee[i] = __expf(l[i] - m); s += ee[i]; }
    s += __shfl_xor(s, 1, 64);
    s += __shfl_xor(s, 2, 64);
    s += __shfl_xor(s, 4, 64);
    const float inv = 1.0f / s;
    if (lane < 8) {
        float4 p0 = make_float4(ee[0] * inv, ee[1] * inv, ee[2] * inv, ee[3] * inv);
        float4 p1 = make_float4(ee[4] * inv, ee[5] * inv, ee[6] * inv, ee[7] * inv);
        *reinterpret_cast<float4*>(&out[(size_t)node * OUT_DIM + c8]) = p0;
        *reinterpret_cast<float4*>(&out[(size_t)node * OUT_DIM + c8 + 4]) = p1;
        float4 q0 = make_float4(l[0], l[1], l[2], l[3]);
        float4 q1 = make_float4(l[4], l[5], l[6], l[7]);
        float* lg = &out[(size_t)NN * OUT_DIM + (size_t)node * OUT_DIM + c8];
        *reinterpret_cast<float4*>(lg) = q0;
        *reinterpret_cast<float4*>(lg + 4) = q1;
    }
}

static inline size_t align_up(size_t x, size_t a) { return (x + a - 1) & ~(a - 1); }

extern "C" void kernel_launch(void* const* d_in, const int* in_sizes, int n_in,
                              void* d_out, int out_size, void* d_ws, size_t ws_size,
                              hipStream_t stream) {
    (void)in_sizes; (void)n_in; (void)out_size;
    const float* h = (const float*)d_in[0];
    const float* W1 = (const float*)d_in[1];
    const float* b1 = (const float*)d_in[2];
    const float* W2 = (const float*)d_in[3];
    const float* b2 = (const float*)d_in[4];
    const int* src = (const int*)d_in[5];
    const int* dst = (const int*)d_in[6];
    float* out = (float*)d_out;

    char* ws = (char*)d_ws;
    size_t off = 0;
    auto alloc = [&](size_t bytes) {
        void* p = (void*)(ws + off);
        off = align_up(off + bytes, 512);
        return p;
    };
    unsigned* cnt_out = (unsigned*)alloc(NN * 4);
    unsigned short* cnt2dD = (unsigned short*)alloc((size_t)NBLK * NFB * 2);
    unsigned short* cnt2dS = (unsigned short*)alloc((size_t)NBLK * NFB * 2);
    unsigned* btotD = (unsigned*)alloc(NFB * 4);
    unsigned* btotS = (unsigned*)alloc(NFB * 4);
    unsigned* rsinfo = (unsigned*)alloc(NN * 4);
    float* dsin = (float*)alloc(NN * 4);
    unsigned* ebufD = (unsigned*)alloc((size_t)NFB * CAP * 4);
    unsigned char* ebufS = (unsigned char*)alloc((size_t)NFB * CAP);
    int* csr = (int*)alloc((size_t)NFB * CAP * 4);
    unsigned short* W1t = (unsigned short*)alloc((size_t)HID_DIM * IN_DIM * 2);
    unsigned short* W2t = (unsigned short*)alloc((size_t)OUT_DIM * HID_DIM * 2);
    unsigned short* feat1 = (unsigned short*)alloc((size_t)NN * HID_DIM * 2);
    unsigned short* xs = (unsigned short*)alloc((size_t)NN * HID_DIM * 2);
    unsigned short* feat2 = feat1;  // alias: feat1 dead after spmm1

    if (off > ws_size) {
        fprintf(stderr, "kernel_launch: ws too small: need %zu, have %zu\n", off, ws_size);
        return;
    }

    scat1_kernel<<<NBLK, 256, 0, stream>>>(src, dst, cnt2dD, cnt2dS);
    scanCprep_kernel<<<2 * NFB + PREP_BLKS, 128, 0, stream>>>(cnt2dD, cnt2dS, btotD, btotS,
                                                              W1, W2, W1t, W2t);
    scat2_kernel<<<NBLK, 256, 0, stream>>>(src, dst, cnt2dD, cnt2dS, ebufD, ebufS);
    bsortc_kernel<<<NFB, 256, 0, stream>>>(ebufD, btotD, ebufS, btotS, csr, rsinfo, dsin,
                                           cnt_out);

    gemm1_kernel<<<(NN + 127) / 128, 256, 0, stream>>>(h, W1t, cnt_out, feat1, NN);
    spmm1_kernel<<<(NN + 3) / 4, 256, 0, stream>>>(feat1, csr, rsinfo, dsin, cnt_out, b1, xs);
    gemm2_kernel<<<(NN + 127) / 128, 256, 0, stream>>>(xs, W2t, feat2, NN);
    spmm2_kernel<<<(NN + 3) / 4, 256, 0, stream>>>(feat2, csr, rsinfo, dsin, b2, out);
}